// Round 7
// baseline (15265.906 us; speedup 1.0000x reference)
//
#include <hip/hip_runtime.h>
#include <stdint.h>
#include <stdio.h>

#define T_ 10
#define B_ 16
#define S_ 200
#define D_ 768
#define H_ 300
#define NC_ 4
#define M_ (S_ * B_)   /* 3200 rows per t */
#define K5_ (5 * D_)   /* 3840 */
#define N2_ 2400       /* 2 dirs * 4H */
#define G4_ 1200       /* 4H */
#define HXW_SLOT 2432  /* u32 words per parity slot: 16 b x 152 (150 used, packed bf16 pairs) */
#define HLDS_STRIDE 344 /* u16; 172 u32 per b row */
#define NTILE 130       /* 13 x 10 grid of 256x256 GEMM tiles */

typedef unsigned short u16;
typedef unsigned int u32;
typedef __attribute__((ext_vector_type(8))) short short8;
typedef __attribute__((ext_vector_type(4))) float float4v;
typedef __attribute__((ext_vector_type(4))) unsigned int u32x4;

static __device__ __forceinline__ u16 f2bf(float x) {
  union { float f; u32 u; } v; v.f = x;
  u32 u = v.u;
  u32 r = (u + 0x7FFFu + ((u >> 16) & 1u)) >> 16;
  return (u16)r;
}

static __device__ __forceinline__ void async16(const void* g, void* l) {
  __builtin_amdgcn_global_load_lds((const __attribute__((address_space(1))) u32*)g,
                                   (__attribute__((address_space(3))) u32*)l, 16, 0, 0);
}

static __device__ __forceinline__ float sigmoid_f(float x) {
  return 1.f / (1.f + __expf(-x));
}
static __device__ __forceinline__ float tanh_f(float x) {
  float e = __expf(2.f * x);
  return 1.f - 2.f / (e + 1.f);   // safe at e=inf -> 1, e=0 -> -1
}

// ---------------------------------------------------------------------------
// K0a: build S0 = bf16(seq), SA = a .* seq, SB = b .* seq  (layout [t][s][b][768])
//      plus before-state SA0/SB0 (t=0 before-state weights on seq[0])
// ---------------------------------------------------------------------------
__global__ void k_prep_s(const float* __restrict__ seq,
                         const float* __restrict__ sp, const float* __restrict__ ep,
                         const float* __restrict__ cp,
                         const float* __restrict__ bsp, const float* __restrict__ bep,
                         const float* __restrict__ bcp,
                         const float* __restrict__ um, const float* __restrict__ nm,
                         const float* __restrict__ am,
                         u16* __restrict__ s0, u16* __restrict__ sa, u16* __restrict__ sb,
                         u16* __restrict__ sa0, u16* __restrict__ sb0) {
  int bid = blockIdx.x;
  int tid = threadIdx.x;  // 256
  if (bid < T_ * M_) {
    int t = bid / M_;
    int r = bid % M_;
    int s = r >> 4, b = r & 15;
    float c0 = cp[(t * B_ + b) * NC_ + 0];
    float c1 = cp[(t * B_ + b) * NC_ + 1];
    float c2 = cp[(t * B_ + b) * NC_ + 2];
    int mi = (b * T_ + t) * S_ + s;
    float w = am[mi] * c0 + um[mi] * c1 + nm[mi] * c2;
    float aw = sp[(t * B_ + b) * S_ + s] * w;
    float bw = ep[(t * B_ + b) * S_ + s] * w;
    const float* x = seq + ((size_t)(t * B_ + b) * S_ + s) * D_;
    size_t ob = (size_t)bid * D_;
    for (int d = tid; d < D_; d += 256) {
      float xv = x[d];
      s0[ob + d] = f2bf(xv);
      sa[ob + d] = f2bf(aw * xv);
      sb[ob + d] = f2bf(bw * xv);
    }
  } else {
    int r = bid - T_ * M_;
    int s = r >> 4, b = r & 15;
    float c0 = bcp[b * NC_ + 0], c1 = bcp[b * NC_ + 1], c2 = bcp[b * NC_ + 2];
    int mi = (b * T_ + 0) * S_ + s;
    float w = am[mi] * c0 + um[mi] * c1 + nm[mi] * c2;
    float aw = bsp[b * S_ + s] * w;
    float bw = bep[b * S_ + s] * w;
    const float* x = seq + ((size_t)b * S_ + s) * D_;
    size_t ob = (size_t)r * D_;
    for (int d = tid; d < D_; d += 256) {
      float xv = x[d];
      sa0[ob + d] = f2bf(aw * xv);
      sb0[ob + d] = f2bf(bw * xv);
    }
  }
}

// ---------------------------------------------------------------------------
// K0b: Wcat bf16 [2400][3840], Whh padded bf16 [2][1200][320], bias=bih+bhh,
//      d_out seeded with bcls, hxw payload + tagb (per-WG step tags) zeroed
// ---------------------------------------------------------------------------
__global__ void k_prep_w(const float* __restrict__ wf, const float* __restrict__ wb,
                         const float* __restrict__ whf, const float* __restrict__ whb,
                         const float* __restrict__ bihf, const float* __restrict__ bhhf,
                         const float* __restrict__ bihb, const float* __restrict__ bhhb,
                         const float* __restrict__ bcls,
                         u16* __restrict__ wcat, u16* __restrict__ whh,
                         float* __restrict__ bias, float* __restrict__ outp,
                         u32* __restrict__ hxw, u32* __restrict__ tagb) {
  int bid = blockIdx.x, tid = threadIdx.x;
  if (bid < N2_) {
    const float* src = bid < G4_ ? wf + (size_t)bid * K5_ : wb + (size_t)(bid - G4_) * K5_;
    u16* dst = wcat + (size_t)bid * K5_;
    for (int k = tid; k < K5_; k += 256) dst[k] = f2bf(src[k]);
  } else if (bid < N2_ + 2 * G4_) {
    int r = bid - N2_;
    int dir = r / G4_, n = r % G4_;
    const float* src = (dir ? whb : whf) + (size_t)n * H_;
    u16* dst = whh + (size_t)(dir * G4_ + n) * 320;
    for (int k = tid; k < 320; k += 256) dst[k] = (k < H_) ? f2bf(src[k]) : (u16)0;
  } else {
    for (int i = tid; i < 2 * G4_; i += 256) {
      int dir = i / G4_, n = i % G4_;
      bias[i] = dir ? (bihb[n] + bhhb[n]) : (bihf[n] + bhhf[n]);
    }
    for (int i = tid; i < T_ * B_ * NC_; i += 256) outp[i] = bcls[i & 3];
    for (int i = tid; i < 2 * 2 * HXW_SLOT; i += 256) hxw[i] = 0;
    if (tid < 32) tagb[tid] = 0;  // tag 0 = nothing published
  }
}

// ---------------------------------------------------------------------------
// K_MAIN: fused launch per t.
//   steady==1 (grid 176):
//     bid%8==0, bid/8<5  -> LSTM wg w=bid/8, handling BOTH directions
//     bid%8>=2           -> GEMM worker, tile = (bid/8)*6 + bid%8-2
//     else               -> exit
//   steady==0 (grid 130): pure GEMM prologue, tile = bid.
//
// LSTM ping-pong: each iteration advances BOTH dirs one step:
//   phase0: poll dir0 tags/payload -> sync -> [tid0: tag1 := g] -> MFMA0 ->
//           sync -> gates0 -> publish0 h(g+1)
//   phase1: poll dir1 tags/payload -> sync -> [tid0: tag0 := g+1] -> MFMA1 ->
//           sync -> gates1 -> publish1 h(g+1)
// Each dir's publish->poll gap spans the OTHER dir's compute phase, so the
// exchange RTT (publish-ack + tag visibility + detect + payload read) hides
// under ~1300 cyc of MFMA+gates instead of serializing. The deferred tag
// store reuses the phase sync as its data-drain (syncthreads waits vmcnt(0)).
// Protocol/induction identical to R6, two independent instances.
// ---------------------------------------------------------------------------
__global__ __launch_bounds__(1024) void k_main(
    const u16* __restrict__ s0, const u16* __restrict__ sa, const u16* __restrict__ sb,
    const u16* __restrict__ sa0, const u16* __restrict__ sb0,
    const u16* __restrict__ wcat, float* __restrict__ zbase,
    const u16* __restrict__ whh, const float* __restrict__ bias,
    const float* __restrict__ wcls, u32* __restrict__ hxw, u32* __restrict__ tagb,
    float* __restrict__ outp, float* __restrict__ cst,
    int t_lstm, int t_gemm, int steady) {
  __shared__ __align__(16) char lds_raw[40960];

  int tid = threadIdx.x;
  int lane = tid & 63, wv = tid >> 6;
  int bid = (int)blockIdx.x;

  int w = 0, tile = -1;
  bool lstm_role = false;
  if (steady) {
    int grp = bid >> 3, sub = bid & 7;
    if (sub == 0) {
      if (grp < 5) { lstm_role = true; w = grp; }
      else return;
    } else if (sub >= 2) {
      if (t_gemm < 0) return;
      tile = grp * 6 + (sub - 2);
      if (tile >= NTILE) return;
    } else {
      return;
    }
  } else {
    tile = bid;
  }

  if (!lstm_role) {
    // ---------------- GEMM path: one 256x256 tile ----------------
    int mt = tile % 13, nt = tile / 13;
    int m0 = mt * 256, n0 = nt * 256;
    u16* As = (u16*)lds_raw;             // [256][32]
    u16* Bs = (u16*)(lds_raw + 16384);   // [256][32]
    int wm = wv & 3, wn = wv >> 2;

    const u16* ap[5];
    ap[0] = s0 + (size_t)t_gemm * M_ * D_;
    ap[1] = sa + (size_t)t_gemm * M_ * D_;
    ap[2] = sb + (size_t)t_gemm * M_ * D_;
    ap[3] = t_gemm ? sa + (size_t)(t_gemm - 1) * M_ * D_ : sa0;
    ap[4] = t_gemm ? sb + (size_t)(t_gemm - 1) * M_ * D_ : sb0;
    float* z = zbase + (size_t)(t_gemm & 1) * M_ * N2_;

    float4v acc[4][4];
#pragma unroll
    for (int i = 0; i < 4; i++)
#pragma unroll
      for (int j = 0; j < 4; j++) acc[i][j] = (float4v){0.f, 0.f, 0.f, 0.f};

    int rowA = tid >> 2;   // 0..255
    int seg = tid & 3;
    int mr = m0 + rowA; if (mr > M_ - 1) mr = M_ - 1;
    int nr = n0 + rowA; if (nr > N2_ - 1) nr = N2_ - 1;

    for (int which = 0; which < 5; ++which) {
      const u16* ab = which == 0 ? ap[0] : which == 1 ? ap[1] : which == 2 ? ap[2]
                      : which == 3 ? ap[3] : ap[4];
      for (int kk = 0; kk < 24; ++kk) {
        int kof = kk * 32;
        async16(ab + (size_t)mr * D_ + kof + seg * 8, As + wv * 512);
        async16(wcat + (size_t)nr * K5_ + which * D_ + kof + seg * 8, Bs + wv * 512);
        __syncthreads();
        short8 af[4], bf[4];
#pragma unroll
        for (int i = 0; i < 4; i++) {
          af[i] = *(const short8*)&As[(wm * 64 + i * 16 + (lane & 15)) * 32 + (lane >> 4) * 8];
          bf[i] = *(const short8*)&Bs[(wn * 64 + i * 16 + (lane & 15)) * 32 + (lane >> 4) * 8];
        }
#pragma unroll
        for (int i = 0; i < 4; i++)
#pragma unroll
          for (int j = 0; j < 4; j++)
            acc[i][j] = __builtin_amdgcn_mfma_f32_16x16x32_bf16(af[i], bf[j], acc[i][j], 0, 0, 0);
        __syncthreads();
      }
    }
#pragma unroll
    for (int i = 0; i < 4; i++) {
      int m = m0 + wm * 64 + i * 16 + (lane >> 4) * 4;
#pragma unroll
      for (int j = 0; j < 4; j++) {
        int n = n0 + wn * 64 + j * 16 + (lane & 15);
        if (n < N2_) {
#pragma unroll
          for (int r = 0; r < 4; r++)
            if (m + r < M_) z[(size_t)(m + r) * N2_ + n] = acc[i][j][r];
        }
      }
    }
    return;
  }

  // ---------------- LSTM path (both dirs in this WG) ----------------
  u16* h_lds0 = (u16*)lds_raw;                       // [16][344]
  u16* h_lds1 = (u16*)(lds_raw + 11008);             // [16][344]
  u32* h32_0 = (u32*)lds_raw;
  u32* h32_1 = (u32*)(lds_raw + 11008);
  float* smem = (float*)(lds_raw + 22016);           // 4160 floats (shared serially)

  int t = t_lstm;
  int base = t * S_;
  int gate = wv >> 2, q = wv & 3;
  const float* z = zbase + (size_t)(t & 1) * M_ * N2_;

  // persistent Whh B-fragments for BOTH dirs
  short8 bfr[2][10];
#pragma unroll
  for (int d = 0; d < 2; ++d) {
    int col = lane & 15;
    int u = w * 64 + q * 16 + col;
    int krow = (lane >> 4) * 8;
    if (u < H_) {
      const u16* bw_ = whh + (size_t)(d * G4_ + gate * H_ + u) * 320 + krow;
#pragma unroll
      for (int kk = 0; kk < 10; ++kk) bfr[d][kk] = *(const short8*)(bw_ + kk * 32);
    } else {
#pragma unroll
      for (int kk = 0; kk < 10; ++kk) bfr[d][kk] = (short8){0, 0, 0, 0, 0, 0, 0, 0};
    }
  }

  int b = tid >> 6;
  int u_loc = tid & 63;
  int u_glob = w * 64 + u_loc;
  bool active = u_glob < H_;
  float bias_r[2][4];
#pragma unroll
  for (int d = 0; d < 2; ++d)
#pragma unroll
    for (int g = 0; g < 4; ++g)
      bias_r[d][g] = active ? bias[d * G4_ + g * H_ + u_glob] : 0.f;

  float cs0 = t > 0 ? cst[(0 * 5 + w) * 1024 + tid] : 0.f;
  float cs1 = t > 0 ? cst[(1 * 5 + w) * 1024 + tid] : 0.f;
  float cls0[4] = {0.f, 0.f, 0.f, 0.f};
  float cls1[4] = {0.f, 0.f, 0.f, 0.f};

  for (int i = tid; i < 5504; i += 1024) { h_lds0[i] = 0; h_lds1[i] = 0; }
  __syncthreads();

  u32* hx0 = hxw;                    // dir0: 2 parity slots
  u32* hx1 = hxw + 2 * HXW_SLOT;     // dir1
  u32* tg0 = tagb;                   // dir0 tags [0..4]
  u32* tg1 = tagb + 16;              // dir1 tags

  // bulk-read geometry: tid<608 read dwordx4 at word tid*4 (608*4 = 2432 = slot)
  bool rd_on = tid < 608;
  int rdw = tid * 4;
  int rlofs[4];
  u32 rmask = 0;
#pragma unroll
  for (int k = 0; k < 4; ++k) {
    int i = rdw + k;
    rlofs[k] = 0;
    if (rd_on && i < 2432) {
      int bb = i / 152;
      int jj = i - bb * 152;
      if (jj < 150) { rlofs[k] = bb * 172 + jj; rmask |= 1u << k; }
    }
  }

  for (int s_mod = 0; s_mod < S_; ++s_mod) {
    int g = base + s_mod;
    int s_in0 = s_mod;
    int s_in1 = S_ - 1 - s_mod;

    // =============== phase 0 : dir0 ===============
    float z0v[4] = {0.f, 0.f, 0.f, 0.f}, wc0[4] = {0.f, 0.f, 0.f, 0.f};
    if (active) {
      const float* zr = z + (size_t)(s_in0 * B_ + b) * N2_;
      int ycol = s_in0 * 600 + u_glob;
#pragma unroll
      for (int gg = 0; gg < 4; ++gg) z0v[gg] = zr[gg * H_ + u_glob];
#pragma unroll
      for (int n = 0; n < 4; ++n) wc0[n] = wcls[(size_t)n * (S_ * 600) + ycol];
    }
    if (g > 0) {
      int tries = 0;
      for (;;) {
        u32x4 tA; u32 tB;
        asm volatile("global_load_dwordx4 %0, %2, off sc1\n\t"
                     "global_load_dword %1, %3, off sc1\n\t"
                     "s_waitcnt vmcnt(0)"
                     : "=&v"(tA), "=&v"(tB) : "v"(tg0), "v"(tg0 + 4) : "memory");
        if (tA[0] >= (u32)g && tA[1] >= (u32)g && tA[2] >= (u32)g &&
            tA[3] >= (u32)g && tB >= (u32)g) break;
        if (++tries >= (1 << 20)) break;
      }
      __builtin_amdgcn_sched_barrier(0);
      const u32* src = hx0 + (g & 1) * HXW_SLOT;
      if (rd_on) {
        u32x4 dd;
        asm volatile("global_load_dwordx4 %0, %1, off sc1\n\t"
                     "s_waitcnt vmcnt(0)"
                     : "=&v"(dd) : "v"(src + rdw) : "memory");
#pragma unroll
        for (int k = 0; k < 4; ++k)
          if (rmask & (1u << k)) h32_0[rlofs[k]] = dd[k];
      }
    }
    __syncthreads();   // LDS0 ready; drains prev iter's publish1 stores
    if (tid == 0)      // certify dir1's h(g) (published end of prev iter)
      __hip_atomic_store(&tg1[w], (u32)g, __ATOMIC_RELAXED, __HIP_MEMORY_SCOPE_AGENT);

    {  // MFMA dir0
      float4v acc = (float4v){0.f, 0.f, 0.f, 0.f};
      int m = lane & 15;
      int kbase = (lane >> 4) * 8;
      const u16* hl = h_lds0 + m * HLDS_STRIDE + kbase;
#pragma unroll
      for (int kk = 0; kk < 10; ++kk) {
        short8 af = *(const short8*)(hl + kk * 32);
        acc = __builtin_amdgcn_mfma_f32_16x16x32_bf16(af, bfr[0][kk], acc, 0, 0, 0);
      }
      int col = lane & 15;
      int rb = (lane >> 4) * 4;
#pragma unroll
      for (int r = 0; r < 4; r++)
        smem[(gate * 16 + rb + r) * 65 + q * 16 + col] = acc[r];
    }
    __syncthreads();

    {  // gates dir0 + publish
      float zi = smem[(0 * 16 + b) * 65 + u_loc] + z0v[0] + bias_r[0][0];
      float zf = smem[(1 * 16 + b) * 65 + u_loc] + z0v[1] + bias_r[0][1];
      float zg = smem[(2 * 16 + b) * 65 + u_loc] + z0v[2] + bias_r[0][2];
      float zo = smem[(3 * 16 + b) * 65 + u_loc] + z0v[3] + bias_r[0][3];
      float ig = sigmoid_f(zi), fg = sigmoid_f(zf);
      float gg = tanh_f(zg), og = sigmoid_f(zo);
      cs0 = fg * cs0 + ig * gg;
      float hval = og * tanh_f(cs0);
      u16 hb = f2bf(hval);
      u32 mine = (u32)hb;
      u32 other = (u32)__shfl_xor((int)mine, 1);
      if (active) {
        h_lds0[b * HLDS_STRIDE + u_glob] = hb;
        float rv = hval > 0.f ? hval : 0.f;
#pragma unroll
        for (int n = 0; n < 4; ++n) cls0[n] += rv * wc0[n];
      }
      if (active && !(u_loc & 1)) {
        u32 wrd = mine | (other << 16);
        __hip_atomic_store(&hx0[((g + 1) & 1) * HXW_SLOT + b * 152 + (u_glob >> 1)],
                           wrd, __ATOMIC_RELAXED, __HIP_MEMORY_SCOPE_AGENT);
      }
    }

    // =============== phase 1 : dir1 ===============
    float z1v[4] = {0.f, 0.f, 0.f, 0.f}, wc1[4] = {0.f, 0.f, 0.f, 0.f};
    if (active) {
      const float* zr = z + (size_t)(s_in1 * B_ + b) * N2_ + G4_;
      int ycol = s_in1 * 600 + H_ + u_glob;
#pragma unroll
      for (int gg = 0; gg < 4; ++gg) z1v[gg] = zr[gg * H_ + u_glob];
#pragma unroll
      for (int n = 0; n < 4; ++n) wc1[n] = wcls[(size_t)n * (S_ * 600) + ycol];
    }
    if (g > 0) {
      int tries = 0;
      for (;;) {
        u32x4 tA; u32 tB;
        asm volatile("global_load_dwordx4 %0, %2, off sc1\n\t"
                     "global_load_dword %1, %3, off sc1\n\t"
                     "s_waitcnt vmcnt(0)"
                     : "=&v"(tA), "=&v"(tB) : "v"(tg1), "v"(tg1 + 4) : "memory");
        if (tA[0] >= (u32)g && tA[1] >= (u32)g && tA[2] >= (u32)g &&
            tA[3] >= (u32)g && tB >= (u32)g) break;
        if (++tries >= (1 << 20)) break;
      }
      __builtin_amdgcn_sched_barrier(0);
      const u32* src = hx1 + (g & 1) * HXW_SLOT;
      if (rd_on) {
        u32x4 dd;
        asm volatile("global_load_dwordx4 %0, %1, off sc1\n\t"
                     "s_waitcnt vmcnt(0)"
                     : "=&v"(dd) : "v"(src + rdw) : "memory");
#pragma unroll
        for (int k = 0; k < 4; ++k)
          if (rmask & (1u << k)) h32_1[rlofs[k]] = dd[k];
      }
    }
    __syncthreads();   // LDS1 ready; drains publish0 stores of this iter
    if (tid == 0)      // certify dir0's h(g+1)
      __hip_atomic_store(&tg0[w], (u32)(g + 1), __ATOMIC_RELAXED, __HIP_MEMORY_SCOPE_AGENT);

    {  // MFMA dir1
      float4v acc = (float4v){0.f, 0.f, 0.f, 0.f};
      int m = lane & 15;
      int kbase = (lane >> 4) * 8;
      const u16* hl = h_lds1 + m * HLDS_STRIDE + kbase;
#pragma unroll
      for (int kk = 0; kk < 10; ++kk) {
        short8 af = *(const short8*)(hl + kk * 32);
        acc = __builtin_amdgcn_mfma_f32_16x16x32_bf16(af, bfr[1][kk], acc, 0, 0, 0);
      }
      int col = lane & 15;
      int rb = (lane >> 4) * 4;
#pragma unroll
      for (int r = 0; r < 4; r++)
        smem[(gate * 16 + rb + r) * 65 + q * 16 + col] = acc[r];
    }
    __syncthreads();

    {  // gates dir1 + publish
      float zi = smem[(0 * 16 + b) * 65 + u_loc] + z1v[0] + bias_r[1][0];
      float zf = smem[(1 * 16 + b) * 65 + u_loc] + z1v[1] + bias_r[1][1];
      float zg = smem[(2 * 16 + b) * 65 + u_loc] + z1v[2] + bias_r[1][2];
      float zo = smem[(3 * 16 + b) * 65 + u_loc] + z1v[3] + bias_r[1][3];
      float ig = sigmoid_f(zi), fg = sigmoid_f(zf);
      float gg = tanh_f(zg), og = sigmoid_f(zo);
      cs1 = fg * cs1 + ig * gg;
      float hval = og * tanh_f(cs1);
      u16 hb = f2bf(hval);
      u32 mine = (u32)hb;
      u32 other = (u32)__shfl_xor((int)mine, 1);
      if (active) {
        h_lds1[b * HLDS_STRIDE + u_glob] = hb;
        float rv = hval > 0.f ? hval : 0.f;
#pragma unroll
        for (int n = 0; n < 4; ++n) cls1[n] += rv * wc1[n];
      }
      if (active && !(u_loc & 1)) {
        u32 wrd = mine | (other << 16);
        __hip_atomic_store(&hx1[((g + 1) & 1) * HXW_SLOT + b * 152 + (u_glob >> 1)],
                           wrd, __ATOMIC_RELAXED, __HIP_MEMORY_SCOPE_AGENT);
      }
    }

    if (s_mod == S_ - 1) {
      // classifier reduce, dir0 then dir1 (smem reused; sync-separated)
      __syncthreads();
#pragma unroll
      for (int n = 0; n < 4; ++n) smem[(b * 64 + u_loc) * 4 + n] = cls0[n];
      __syncthreads();
      if (tid < B_ * NC_) {
        int bb = tid >> 2, n = tid & 3;
        float s = 0.f;
        for (int u = 0; u < 64; ++u) s += smem[(bb * 64 + u) * 4 + n];
        atomicAdd(&outp[(t * B_ + bb) * NC_ + n], s);
      }
      __syncthreads();
#pragma unroll
      for (int n = 0; n < 4; ++n) smem[(b * 64 + u_loc) * 4 + n] = cls1[n];
      __syncthreads();
      if (tid < B_ * NC_) {
        int bb = tid >> 2, n = tid & 3;
        float s = 0.f;
        for (int u = 0; u < 64; ++u) s += smem[(bb * 64 + u) * 4 + n];
        atomicAdd(&outp[(t * B_ + bb) * NC_ + n], s);
      }
    }
  }
  // flush: dir1's final publish needs its tag (drain via syncthreads first)
  __syncthreads();
  if (tid == 0)
    __hip_atomic_store(&tg1[w], (u32)(base + S_), __ATOMIC_RELAXED, __HIP_MEMORY_SCOPE_AGENT);
  cst[(0 * 5 + w) * 1024 + tid] = cs0;
  cst[(1 * 5 + w) * 1024 + tid] = cs1;
}

// ---------------------------------------------------------------------------
extern "C" void kernel_launch(void* const* d_in, const int* in_sizes, int n_in,
                              void* d_out, int out_size, void* d_ws, size_t ws_size,
                              hipStream_t stream) {
  const float* seq = (const float*)d_in[1];
  const float* sp = (const float*)d_in[2];
  const float* ep = (const float*)d_in[3];
  const float* cp = (const float*)d_in[4];
  const float* bsp = (const float*)d_in[5];
  const float* bep = (const float*)d_in[6];
  const float* bcp = (const float*)d_in[7];
  const float* um = (const float*)d_in[8];
  const float* nm = (const float*)d_in[9];
  const float* am = (const float*)d_in[10];
  const float* wihf = (const float*)d_in[11];
  const float* whhf = (const float*)d_in[12];
  const float* bihf = (const float*)d_in[13];
  const float* bhhf = (const float*)d_in[14];
  const float* wihb = (const float*)d_in[15];
  const float* whhb = (const float*)d_in[16];
  const float* bihb = (const float*)d_in[17];
  const float* bhhb = (const float*)d_in[18];
  const float* wcls = (const float*)d_in[19];
  const float* bcls = (const float*)d_in[20];

  char* ws = (char*)d_ws;
  size_t off = 0;
  auto alloc = [&](size_t bytes) -> char* {
    char* p = ws + off;
    off += (bytes + 255) & ~(size_t)255;
    return p;
  };
  u16* S0 = (u16*)alloc((size_t)T_ * M_ * D_ * 2);
  u16* SA = (u16*)alloc((size_t)T_ * M_ * D_ * 2);
  u16* SB = (u16*)alloc((size_t)T_ * M_ * D_ * 2);
  u16* SA0 = (u16*)alloc((size_t)M_ * D_ * 2);
  u16* SB0 = (u16*)alloc((size_t)M_ * D_ * 2);
  u16* WCAT = (u16*)alloc((size_t)N2_ * K5_ * 2);
  u16* WHH = (u16*)alloc((size_t)2 * G4_ * 320 * 2);
  float* BIAS = (float*)alloc((size_t)2 * G4_ * 4);
  float* Z = (float*)alloc((size_t)2 * M_ * N2_ * 4);   // parity double-buffer
  u32* HXW = (u32*)alloc((size_t)2 * 2 * HXW_SLOT * 4); // packed h, 2 dirs x 2 slots
  u32* TAGB = (u32*)alloc((size_t)32 * 4);              // per-WG step tags
  float* CST = (float*)alloc((size_t)10 * 1024 * 4);

  if (off > ws_size) {
    fprintf(stderr, "[kernel] ws too small: need %zu, have %zu\n", off, ws_size);
    return;
  }

  hipLaunchKernelGGL(k_prep_s, dim3(T_ * M_ + M_), dim3(256), 0, stream,
                     seq, sp, ep, cp, bsp, bep, bcp, um, nm, am, S0, SA, SB, SA0, SB0);
  hipLaunchKernelGGL(k_prep_w, dim3(N2_ + 2 * G4_ + 1), dim3(256), 0, stream,
                     wihf, wihb, whhf, whhb, bihf, bhhf, bihb, bhhb, bcls,
                     WCAT, WHH, BIAS, (float*)d_out, HXW, TAGB);
  // prologue: t=0 GEMM alone (fills Z slot 0), full-machine spread
  hipLaunchKernelGGL(k_main, dim3(NTILE), dim3(1024), 0, stream,
                     S0, SA, SB, SA0, SB0, WCAT, Z, WHH, BIAS, wcls, HXW, TAGB,
                     (float*)d_out, CST, 0, 0, 0);
  for (int t = 0; t < T_; ++t) {
    // LSTM(t) (5 dual-dir WGs) + GEMM(t+1) hidden underneath
    hipLaunchKernelGGL(k_main, dim3(176), dim3(1024), 0, stream,
                       S0, SA, SB, SA0, SB0, WCAT, Z, WHH, BIAS, wcls, HXW, TAGB,
                       (float*)d_out, CST, t, (t < T_ - 1) ? t + 1 : -1, 1);
  }
}

// Round 8
// 5696.639 us; speedup vs baseline: 2.6798x; 2.6798x over previous
//
#include <hip/hip_runtime.h>
#include <stdint.h>
#include <stdio.h>

#define T_ 10
#define B_ 16
#define S_ 200
#define D_ 768
#define H_ 300
#define NC_ 4
#define M_ (S_ * B_)   /* 3200 rows per t */
#define K5_ (5 * D_)   /* 3840 */
#define N2_ 2400       /* 2 dirs * 4H */
#define G4_ 1200       /* 4H */
#define HXW_SLOT 2432  /* u32 words per parity slot: 16 b x 152 (150 used, packed bf16 pairs) */
#define HLDS_STRIDE 344 /* u16; 172 u32 per b row */
#define NTILE 130       /* 13 x 10 grid of 256x256 GEMM tiles */

typedef unsigned short u16;
typedef unsigned int u32;
typedef __attribute__((ext_vector_type(8))) short short8;
typedef __attribute__((ext_vector_type(4))) float float4v;
typedef __attribute__((ext_vector_type(4))) unsigned int u32x4;

static __device__ __forceinline__ u16 f2bf(float x) {
  union { float f; u32 u; } v; v.f = x;
  u32 u = v.u;
  u32 r = (u + 0x7FFFu + ((u >> 16) & 1u)) >> 16;
  return (u16)r;
}

static __device__ __forceinline__ void async16(const void* g, void* l) {
  __builtin_amdgcn_global_load_lds((const __attribute__((address_space(1))) u32*)g,
                                   (__attribute__((address_space(3))) u32*)l, 16, 0, 0);
}

static __device__ __forceinline__ float sigmoid_f(float x) {
  return 1.f / (1.f + __expf(-x));
}
static __device__ __forceinline__ float tanh_f(float x) {
  float e = __expf(2.f * x);
  return 1.f - 2.f / (e + 1.f);   // safe at e=inf -> 1, e=0 -> -1
}

// ---------------------------------------------------------------------------
// K0a: build S0 = bf16(seq), SA = a .* seq, SB = b .* seq  (layout [t][s][b][768])
//      plus before-state SA0/SB0 (t=0 before-state weights on seq[0])
// ---------------------------------------------------------------------------
__global__ void k_prep_s(const float* __restrict__ seq,
                         const float* __restrict__ sp, const float* __restrict__ ep,
                         const float* __restrict__ cp,
                         const float* __restrict__ bsp, const float* __restrict__ bep,
                         const float* __restrict__ bcp,
                         const float* __restrict__ um, const float* __restrict__ nm,
                         const float* __restrict__ am,
                         u16* __restrict__ s0, u16* __restrict__ sa, u16* __restrict__ sb,
                         u16* __restrict__ sa0, u16* __restrict__ sb0) {
  int bid = blockIdx.x;
  int tid = threadIdx.x;  // 256
  if (bid < T_ * M_) {
    int t = bid / M_;
    int r = bid % M_;
    int s = r >> 4, b = r & 15;
    float c0 = cp[(t * B_ + b) * NC_ + 0];
    float c1 = cp[(t * B_ + b) * NC_ + 1];
    float c2 = cp[(t * B_ + b) * NC_ + 2];
    int mi = (b * T_ + t) * S_ + s;
    float w = am[mi] * c0 + um[mi] * c1 + nm[mi] * c2;
    float aw = sp[(t * B_ + b) * S_ + s] * w;
    float bw = ep[(t * B_ + b) * S_ + s] * w;
    const float* x = seq + ((size_t)(t * B_ + b) * S_ + s) * D_;
    size_t ob = (size_t)bid * D_;
    for (int d = tid; d < D_; d += 256) {
      float xv = x[d];
      s0[ob + d] = f2bf(xv);
      sa[ob + d] = f2bf(aw * xv);
      sb[ob + d] = f2bf(bw * xv);
    }
  } else {
    int r = bid - T_ * M_;
    int s = r >> 4, b = r & 15;
    float c0 = bcp[b * NC_ + 0], c1 = bcp[b * NC_ + 1], c2 = bcp[b * NC_ + 2];
    int mi = (b * T_ + 0) * S_ + s;
    float w = am[mi] * c0 + um[mi] * c1 + nm[mi] * c2;
    float aw = bsp[b * S_ + s] * w;
    float bw = bep[b * S_ + s] * w;
    const float* x = seq + ((size_t)b * S_ + s) * D_;
    size_t ob = (size_t)r * D_;
    for (int d = tid; d < D_; d += 256) {
      float xv = x[d];
      sa0[ob + d] = f2bf(aw * xv);
      sb0[ob + d] = f2bf(bw * xv);
    }
  }
}

// ---------------------------------------------------------------------------
// K0b: Wcat bf16 [2400][3840], Whh padded bf16 [2][1200][320], bias=bih+bhh,
//      d_out seeded with bcls, hxw payload + tagb (per-WG step tags) zeroed
// ---------------------------------------------------------------------------
__global__ void k_prep_w(const float* __restrict__ wf, const float* __restrict__ wb,
                         const float* __restrict__ whf, const float* __restrict__ whb,
                         const float* __restrict__ bihf, const float* __restrict__ bhhf,
                         const float* __restrict__ bihb, const float* __restrict__ bhhb,
                         const float* __restrict__ bcls,
                         u16* __restrict__ wcat, u16* __restrict__ whh,
                         float* __restrict__ bias, float* __restrict__ outp,
                         u32* __restrict__ hxw, u32* __restrict__ tagb) {
  int bid = blockIdx.x, tid = threadIdx.x;
  if (bid < N2_) {
    const float* src = bid < G4_ ? wf + (size_t)bid * K5_ : wb + (size_t)(bid - G4_) * K5_;
    u16* dst = wcat + (size_t)bid * K5_;
    for (int k = tid; k < K5_; k += 256) dst[k] = f2bf(src[k]);
  } else if (bid < N2_ + 2 * G4_) {
    int r = bid - N2_;
    int dir = r / G4_, n = r % G4_;
    const float* src = (dir ? whb : whf) + (size_t)n * H_;
    u16* dst = whh + (size_t)(dir * G4_ + n) * 320;
    for (int k = tid; k < 320; k += 256) dst[k] = (k < H_) ? f2bf(src[k]) : (u16)0;
  } else {
    for (int i = tid; i < 2 * G4_; i += 256) {
      int dir = i / G4_, n = i % G4_;
      bias[i] = dir ? (bihb[n] + bhhb[n]) : (bihf[n] + bhhf[n]);
    }
    for (int i = tid; i < T_ * B_ * NC_; i += 256) outp[i] = bcls[i & 3];
    for (int i = tid; i < 2 * 2 * HXW_SLOT; i += 256) hxw[i] = 0;
    if (tid < 32) tagb[tid] = 0;  // tag 0 = nothing published
  }
}

// ---------------------------------------------------------------------------
// K_MAIN: fused launch per t, XCD-aware role map (blockIdx%8 round-robins
// over the 8 XCDs; if that mapping ever changes, only SPEED is affected —
// all exchange traffic is agent-scope/MALL, placement-independent).
//   steady==1 (grid 176):
//     bid%8==0, bid/8<5  -> LSTM dir0 wg w=bid/8
//     bid%8==1, bid/8<5  -> LSTM dir1 wg w=bid/8
//     bid%8>=2           -> GEMM worker, tile = (bid/8)*6 + bid%8-2
//   steady==0 (grid 130): pure GEMM prologue, tile = bid.
//
// h-exchange (one-tag-per-WG protocol, SINGLE-LANE polling):
//   payload: packed bf16 pairs, word i = b*152 + u/2, parity slot (g+1)&1,
//            stored relaxed-agent (contiguous per wave -> few lines).
//   publish: data stores -> __syncthreads() (drains vmcnt(0), data at MALL)
//            -> tid0 stores tag g+1 (one word).
//   consume: ONLY lane 0 of each wave spins on the 5-tag line (divergent if;
//            other 63 lanes wait at reconvergence). This cuts same-line load
//            pressure 64x so the publisher's tag store isn't queued behind
//            thousands of polling reads. Each wave's payload loads are issued
//            after ITS lane-0 detect load returned -> the R6 ordering argument
//            (tag's MALL arrival postdates data's; our reads postdate the tag
//            read) holds per-wave.
//   slot overwrite safety: unchanged R6 induction.
// ---------------------------------------------------------------------------
__global__ __launch_bounds__(1024) void k_main(
    const u16* __restrict__ s0, const u16* __restrict__ sa, const u16* __restrict__ sb,
    const u16* __restrict__ sa0, const u16* __restrict__ sb0,
    const u16* __restrict__ wcat, float* __restrict__ zbase,
    const u16* __restrict__ whh, const float* __restrict__ bias,
    const float* __restrict__ wcls, u32* __restrict__ hxw, u32* __restrict__ tagb,
    float* __restrict__ outp, float* __restrict__ cst,
    int t_lstm, int t_gemm, int steady) {
  __shared__ __align__(16) char lds_raw[32768];

  int tid = threadIdx.x;
  int lane = tid & 63, wv = tid >> 6;
  int bid = (int)blockIdx.x;

  int dir = 0, w = 0, tile = -1;
  bool lstm_role = false;
  if (steady) {
    int grp = bid >> 3, sub = bid & 7;
    if (sub < 2) {
      if (grp < 5) { lstm_role = true; dir = sub; w = grp; }
      else return;
    } else {
      if (t_gemm < 0) return;
      tile = grp * 6 + (sub - 2);
      if (tile >= NTILE) return;
    }
  } else {
    tile = bid;
  }

  if (!lstm_role) {
    // ---------------- GEMM path: one 256x256 tile ----------------
    int mt = tile % 13, nt = tile / 13;
    int m0 = mt * 256, n0 = nt * 256;
    u16* As = (u16*)lds_raw;             // [256][32]
    u16* Bs = (u16*)(lds_raw + 16384);   // [256][32]
    int wm = wv & 3, wn = wv >> 2;

    const u16* ap[5];
    ap[0] = s0 + (size_t)t_gemm * M_ * D_;
    ap[1] = sa + (size_t)t_gemm * M_ * D_;
    ap[2] = sb + (size_t)t_gemm * M_ * D_;
    ap[3] = t_gemm ? sa + (size_t)(t_gemm - 1) * M_ * D_ : sa0;
    ap[4] = t_gemm ? sb + (size_t)(t_gemm - 1) * M_ * D_ : sb0;
    float* z = zbase + (size_t)(t_gemm & 1) * M_ * N2_;

    float4v acc[4][4];
#pragma unroll
    for (int i = 0; i < 4; i++)
#pragma unroll
      for (int j = 0; j < 4; j++) acc[i][j] = (float4v){0.f, 0.f, 0.f, 0.f};

    int rowA = tid >> 2;   // 0..255
    int seg = tid & 3;
    int mr = m0 + rowA; if (mr > M_ - 1) mr = M_ - 1;
    int nr = n0 + rowA; if (nr > N2_ - 1) nr = N2_ - 1;

    for (int which = 0; which < 5; ++which) {
      const u16* ab = which == 0 ? ap[0] : which == 1 ? ap[1] : which == 2 ? ap[2]
                      : which == 3 ? ap[3] : ap[4];
      for (int kk = 0; kk < 24; ++kk) {
        int kof = kk * 32;
        async16(ab + (size_t)mr * D_ + kof + seg * 8, As + wv * 512);
        async16(wcat + (size_t)nr * K5_ + which * D_ + kof + seg * 8, Bs + wv * 512);
        __syncthreads();
        short8 af[4], bf[4];
#pragma unroll
        for (int i = 0; i < 4; i++) {
          af[i] = *(const short8*)&As[(wm * 64 + i * 16 + (lane & 15)) * 32 + (lane >> 4) * 8];
          bf[i] = *(const short8*)&Bs[(wn * 64 + i * 16 + (lane & 15)) * 32 + (lane >> 4) * 8];
        }
#pragma unroll
        for (int i = 0; i < 4; i++)
#pragma unroll
          for (int j = 0; j < 4; j++)
            acc[i][j] = __builtin_amdgcn_mfma_f32_16x16x32_bf16(af[i], bf[j], acc[i][j], 0, 0, 0);
        __syncthreads();
      }
    }
#pragma unroll
    for (int i = 0; i < 4; i++) {
      int m = m0 + wm * 64 + i * 16 + (lane >> 4) * 4;
#pragma unroll
      for (int j = 0; j < 4; j++) {
        int n = n0 + wn * 64 + j * 16 + (lane & 15);
        if (n < N2_) {
#pragma unroll
          for (int r = 0; r < 4; r++)
            if (m + r < M_) z[(size_t)(m + r) * N2_ + n] = acc[i][j][r];
        }
      }
    }
    return;
  }

  // ---------------- LSTM path ----------------
  u16* h_lds = (u16*)lds_raw;                              // [16][HLDS_STRIDE]
  u32* h32 = (u32*)lds_raw;                                // same, u32 view (172/b)
  float* smem = (float*)(lds_raw + 16 * HLDS_STRIDE * 2);  // 4160 floats

  int t = t_lstm;
  int wgid = dir * 5 + w;
  int gate = wv >> 2, q = wv & 3;
  const float* z = zbase + (size_t)(t & 1) * M_ * N2_;

  // persistent Whh B-fragments: wave covers cols n = gate*300 + w*64 + q*16 + (lane&15)
  short8 bfr[10];
  {
    int col = lane & 15;
    int u = w * 64 + q * 16 + col;
    int krow = (lane >> 4) * 8;
    if (u < H_) {
      const u16* base = whh + (size_t)(dir * G4_ + gate * H_ + u) * 320 + krow;
#pragma unroll
      for (int kk = 0; kk < 10; ++kk) bfr[kk] = *(const short8*)(base + kk * 32);
    } else {
#pragma unroll
      for (int kk = 0; kk < 10; ++kk) bfr[kk] = (short8){0, 0, 0, 0, 0, 0, 0, 0};
    }
  }

  // thread view for gate/classifier phase
  int b = tid >> 6;
  int u_loc = tid & 63;
  int u_glob = w * 64 + u_loc;
  bool active = u_glob < H_;
  float bias_r[4];
#pragma unroll
  for (int g = 0; g < 4; ++g)
    bias_r[g] = active ? bias[dir * G4_ + g * H_ + u_glob] : 0.f;

  float c_state = t > 0 ? cst[wgid * 1024 + tid] : 0.f;
  float clsacc[4] = {0.f, 0.f, 0.f, 0.f};

  for (int i = tid; i < 16 * HLDS_STRIDE; i += 1024) h_lds[i] = 0;
  __syncthreads();

  u32* hx_base = hxw + dir * 2 * HXW_SLOT;
  u32* tag_base = tagb + dir * 16;   // 5 tags in one cache line

  // bulk-read geometry: tid<608 read dwordx4 at word tid*4 (608*4 = 2432 = slot)
  // word i = b*152 + j holds h[2j], h[2j+1] (valid j<150)
  bool rd_on = tid < 608;
  int rdw = tid * 4;
  int rlofs[4];
  u32 rmask = 0;
#pragma unroll
  for (int k = 0; k < 4; ++k) {
    int i = rdw + k;
    rlofs[k] = 0;
    if (rd_on && i < 2432) {
      int bb = i / 152;
      int jj = i - bb * 152;
      if (jj < 150) { rlofs[k] = bb * 172 + jj; rmask |= 1u << k; }
    }
  }

  for (int s_mod = 0; s_mod < S_; ++s_mod) {
    int g = t * S_ + s_mod;
    int s_in = dir ? (S_ - 1 - s_mod) : s_mod;

    // prefetch (independent of sync): z input row + Wcls column
    float z_in[4] = {0.f, 0.f, 0.f, 0.f}, wc[4] = {0.f, 0.f, 0.f, 0.f};
    if (active) {
      const float* zr = z + (size_t)(s_in * B_ + b) * N2_ + dir * G4_;
      int ycol = s_in * 600 + dir * H_ + u_glob;
#pragma unroll
      for (int gg = 0; gg < 4; ++gg) z_in[gg] = zr[gg * H_ + u_glob];
#pragma unroll
      for (int n = 0; n < 4; ++n) wc[n] = wcls[(size_t)n * (S_ * 600) + ycol];
    }

    if (g > 0) {
      // 1) single-lane tag spin: lane 0 of each wave only (64x fewer pollers;
      //    the publisher's tag store isn't queued behind mass reads)
      if (lane == 0) {
        const u32* tp0 = tag_base;
        const u32* tp4 = tag_base + 4;
        int tries = 0;
        for (;;) {
          u32x4 tA; u32 tB;
          asm volatile("global_load_dwordx4 %0, %2, off sc1\n\t"
                       "global_load_dword %1, %3, off sc1\n\t"
                       "s_waitcnt vmcnt(0)"
                       : "=&v"(tA), "=&v"(tB) : "v"(tp0), "v"(tp4) : "memory");
          if (tA[0] >= (u32)g && tA[1] >= (u32)g && tA[2] >= (u32)g &&
              tA[3] >= (u32)g && tB >= (u32)g) break;
          if (++tries >= (1 << 20)) break;
        }
      }
      __builtin_amdgcn_sched_barrier(0);
      // 2) bulk payload read — issued after this wave's lane-0 detect returned
      const u32* src = hx_base + (g & 1) * HXW_SLOT;
      if (rd_on) {
        u32x4 d;
        asm volatile("global_load_dwordx4 %0, %1, off sc1\n\t"
                     "s_waitcnt vmcnt(0)"
                     : "=&v"(d) : "v"(src + rdw) : "memory");
#pragma unroll
        for (int k = 0; k < 4; ++k)
          if (rmask & (1u << k)) h32[rlofs[k]] = d[k];
      }
      __syncthreads();
    }

    // recurrent GEMV tile via MFMA: D[b][u] = sum_k h[b,k] * Whh[n,k]
    {
      float4v acc = (float4v){0.f, 0.f, 0.f, 0.f};
      int m = lane & 15;
      int kbase = (lane >> 4) * 8;
      const u16* hl = h_lds + m * HLDS_STRIDE + kbase;
#pragma unroll
      for (int kk = 0; kk < 10; ++kk) {
        short8 af = *(const short8*)(hl + kk * 32);
        acc = __builtin_amdgcn_mfma_f32_16x16x32_bf16(af, bfr[kk], acc, 0, 0, 0);
      }
      int col = lane & 15;
      int rb = (lane >> 4) * 4;
#pragma unroll
      for (int r = 0; r < 4; r++)
        smem[(gate * 16 + rb + r) * 65 + q * 16 + col] = acc[r];
    }
    __syncthreads();

    // gates: computed by ALL threads, stores guarded by `active`
    {
      float zi = smem[(0 * 16 + b) * 65 + u_loc] + z_in[0] + bias_r[0];
      float zf = smem[(1 * 16 + b) * 65 + u_loc] + z_in[1] + bias_r[1];
      float zg = smem[(2 * 16 + b) * 65 + u_loc] + z_in[2] + bias_r[2];
      float zo = smem[(3 * 16 + b) * 65 + u_loc] + z_in[3] + bias_r[3];
      float ig = sigmoid_f(zi);
      float fg = sigmoid_f(zf);
      float gg = tanh_f(zg);
      float og = sigmoid_f(zo);
      c_state = fg * c_state + ig * gg;
      float hval = og * tanh_f(c_state);
      u16 hb = f2bf(hval);
      u32 mine = (u32)hb;
      u32 other = (u32)__shfl_xor((int)mine, 1);   // partner h (u^1) — uniform exec
      if (active) {
        h_lds[b * HLDS_STRIDE + u_glob] = hb;      // own value for next step
        float rv = hval > 0.f ? hval : 0.f;
#pragma unroll
        for (int n = 0; n < 4; ++n) clsacc[n] += rv * wc[n];
      }
      if (active && !(u_loc & 1)) {
        u32 wrd = mine | (other << 16);            // h[u] lo, h[u+1] hi
        __hip_atomic_store(&hx_base[((g + 1) & 1) * HXW_SLOT + b * 152 + (u_glob >> 1)],
                           wrd, __ATOMIC_RELAXED, __HIP_MEMORY_SCOPE_AGENT);
      }
    }
    // drain (syncthreads emits s_waitcnt vmcnt(0) before s_barrier), then tag
    __syncthreads();
    if (tid == 0)
      __hip_atomic_store(&tag_base[w], (u32)(g + 1),
                         __ATOMIC_RELAXED, __HIP_MEMORY_SCOPE_AGENT);

    if (s_mod == S_ - 1) {
      __syncthreads();
#pragma unroll
      for (int n = 0; n < 4; ++n) smem[(b * 64 + u_loc) * 4 + n] = clsacc[n];
      __syncthreads();
      if (tid < B_ * NC_) {
        int bb = tid >> 2, n = tid & 3;
        float s = 0.f;
        for (int u = 0; u < 64; ++u) s += smem[(bb * 64 + u) * 4 + n];
        atomicAdd(&outp[(t * B_ + bb) * NC_ + n], s);
      }
    }
  }
  cst[wgid * 1024 + tid] = c_state;
}

// ---------------------------------------------------------------------------
extern "C" void kernel_launch(void* const* d_in, const int* in_sizes, int n_in,
                              void* d_out, int out_size, void* d_ws, size_t ws_size,
                              hipStream_t stream) {
  const float* seq = (const float*)d_in[1];
  const float* sp = (const float*)d_in[2];
  const float* ep = (const float*)d_in[3];
  const float* cp = (const float*)d_in[4];
  const float* bsp = (const float*)d_in[5];
  const float* bep = (const float*)d_in[6];
  const float* bcp = (const float*)d_in[7];
  const float* um = (const float*)d_in[8];
  const float* nm = (const float*)d_in[9];
  const float* am = (const float*)d_in[10];
  const float* wihf = (const float*)d_in[11];
  const float* whhf = (const float*)d_in[12];
  const float* bihf = (const float*)d_in[13];
  const float* bhhf = (const float*)d_in[14];
  const float* wihb = (const float*)d_in[15];
  const float* whhb = (const float*)d_in[16];
  const float* bihb = (const float*)d_in[17];
  const float* bhhb = (const float*)d_in[18];
  const float* wcls = (const float*)d_in[19];
  const float* bcls = (const float*)d_in[20];

  char* ws = (char*)d_ws;
  size_t off = 0;
  auto alloc = [&](size_t bytes) -> char* {
    char* p = ws + off;
    off += (bytes + 255) & ~(size_t)255;
    return p;
  };
  u16* S0 = (u16*)alloc((size_t)T_ * M_ * D_ * 2);
  u16* SA = (u16*)alloc((size_t)T_ * M_ * D_ * 2);
  u16* SB = (u16*)alloc((size_t)T_ * M_ * D_ * 2);
  u16* SA0 = (u16*)alloc((size_t)M_ * D_ * 2);
  u16* SB0 = (u16*)alloc((size_t)M_ * D_ * 2);
  u16* WCAT = (u16*)alloc((size_t)N2_ * K5_ * 2);
  u16* WHH = (u16*)alloc((size_t)2 * G4_ * 320 * 2);
  float* BIAS = (float*)alloc((size_t)2 * G4_ * 4);
  float* Z = (float*)alloc((size_t)2 * M_ * N2_ * 4);   // parity double-buffer
  u32* HXW = (u32*)alloc((size_t)2 * 2 * HXW_SLOT * 4); // packed h, 2 dirs x 2 slots
  u32* TAGB = (u32*)alloc((size_t)32 * 4);              // per-WG step tags (1 line/dir)
  float* CST = (float*)alloc((size_t)10 * 1024 * 4);

  if (off > ws_size) {
    fprintf(stderr, "[kernel] ws too small: need %zu, have %zu\n", off, ws_size);
    return;
  }

  hipLaunchKernelGGL(k_prep_s, dim3(T_ * M_ + M_), dim3(256), 0, stream,
                     seq, sp, ep, cp, bsp, bep, bcp, um, nm, am, S0, SA, SB, SA0, SB0);
  hipLaunchKernelGGL(k_prep_w, dim3(N2_ + 2 * G4_ + 1), dim3(256), 0, stream,
                     wihf, wihb, whhf, whhb, bihf, bhhf, bihb, bhhb, bcls,
                     WCAT, WHH, BIAS, (float*)d_out, HXW, TAGB);
  // prologue: t=0 GEMM alone (fills Z slot 0), full-machine spread
  hipLaunchKernelGGL(k_main, dim3(NTILE), dim3(1024), 0, stream,
                     S0, SA, SB, SA0, SB0, WCAT, Z, WHH, BIAS, wcls, HXW, TAGB,
                     (float*)d_out, CST, 0, 0, 0);
  for (int t = 0; t < T_; ++t) {
    // LSTM(t) on XCD0/1 + GEMM(t+1) on XCDs 2..7 hidden underneath
    hipLaunchKernelGGL(k_main, dim3(176), dim3(1024), 0, stream,
                       S0, SA, SB, SA0, SB0, WCAT, Z, WHH, BIAS, wcls, HXW, TAGB,
                       (float*)d_out, CST, t, (t < T_ - 1) ? t + 1 : -1, 1);
  }
}